// Round 5
// baseline (327.549 us; speedup 1.0000x reference)
//
#include <hip/hip_runtime.h>

typedef __attribute__((ext_vector_type(8))) short bf16x8;
typedef __attribute__((ext_vector_type(4))) float f32x4;

#define T_SEQ 2048
#define EXPM10 4.5399929762484854e-05f  // exp(-10)

// s_waitcnt imm (gfx9 encoding): vmcnt[3:0] | expcnt<<4 | lgkmcnt<<8
#define WAIT_VM8 0xF78  // vmcnt(8)
#define WAIT_VM4 0xF74  // vmcnt(4)
#define WAIT_VM0 0xF70  // vmcnt(0)

__device__ __forceinline__ unsigned short f2bf(float f) {
    unsigned int u = __builtin_bit_cast(unsigned int, f);
    u += 0x7fffu + ((u >> 16) & 1u);
    return (unsigned short)(u >> 16);
}
__device__ __forceinline__ float bf2f(unsigned short u) {
    return __builtin_bit_cast(float, (unsigned int)u << 16);
}

__device__ __forceinline__ void async16(void* lds, const void* g) {
    __builtin_amdgcn_global_load_lds(
        (__attribute__((address_space(1))) void*)g,
        (__attribute__((address_space(3))) void*)lds, 16, 0, 0);
}

// fp32 -> bf16, 4 elems/thread (x activation)
__global__ __launch_bounds__(256) void cvt_bf16(const float* __restrict__ src,
                                                unsigned short* __restrict__ dst, int n4) {
    int i = blockIdx.x * 256 + threadIdx.x;
    if (i < n4) {
        float4 v = ((const float4*)src)[i];
        ushort4 r;
        r.x = f2bf(v.x); r.y = f2bf(v.y); r.z = f2bf(v.z); r.w = f2bf(v.w);
        ((ushort4*)dst)[i] = r;
    }
}

// all 4 weight matrices in one dispatch: wq/wk/wv -> contiguous wqkv, wo -> wob
__global__ __launch_bounds__(256) void cvt_w(const float* __restrict__ wq,
                                             const float* __restrict__ wk,
                                             const float* __restrict__ wv,
                                             const float* __restrict__ wo,
                                             unsigned short* __restrict__ wqkv,
                                             unsigned short* __restrict__ wob) {
    int which = blockIdx.x >> 10;
    int i = (blockIdx.x & 1023) * 256 + threadIdx.x;
    const float* src = which == 0 ? wq : which == 1 ? wk : which == 2 ? wv : wo;
    unsigned short* dst = which < 3 ? wqkv + (size_t)which * 1048576 : wob;
    float4 v = ((const float4*)src)[i];
    ushort4 r;
    r.x = f2bf(v.x); r.y = f2bf(v.y); r.z = f2bf(v.z); r.w = f2bf(v.w);
    ((ushort4*)dst)[i] = r;
}

// 256x256-tile GEMM K-loop, 8 waves (2x4), BK=32, 4 LDS buffers, depth-3.
// R5 changes vs R4 (same proven sync skeleton: one vmcnt(8)+one barrier/K-step):
//  (1) NO sched_barrier fences inside the compute region -> compiler
//      interleaves the 12 ds_read_b128 with the 32 MFMAs using counted
//      lgkmcnt instead of two full lgkmcnt(0) drains per K-step.
//  (2) T2 both-sides XOR swizzle: LDS row = 64B = 4x16B slots;
//      slot ^= (row>>1)&3. Stage side pre-swizzles the GLOBAL source
//      column (LDS dest of global_load_lds stays linear, as required);
//      read side applies the same XOR. Kills the 8-lanes-per-4-bank
//      aliasing (r vs r+2 differ by 128B) -> 2-way (free).
// vmcnt counting unchanged: exactly 4 staging loads per iteration, issued
// after the barrier (sched_barrier right after barrier pins region start;
// sched_barrier at loop end keeps staging inside its iteration).
__device__ __forceinline__ void gemm256_loop(const unsigned short* __restrict__ A,
                                             const unsigned short* __restrict__ B,
                                             int m0, int n0,
                                             unsigned short (*As)[8192],
                                             unsigned short (*Bs)[8192],
                                             f32x4 acc[8][4]) {
    const int K = 1024;
    int tid = threadIdx.x;
    int wave = tid >> 6, lane = tid & 63;
    int r = lane & 15, q = lane >> 4;
    int wr = wave >> 2, wc = wave & 3;
    int qs = q ^ ((r >> 1) & 3);  // swizzled 16B-slot for fragment reads

#pragma unroll
    for (int i = 0; i < 8; i++)
#pragma unroll
        for (int j = 0; j < 4; j++) acc[i][j] = (f32x4){0.f, 0.f, 0.f, 0.f};

    // staging: thread stages 16B to LDS (row rw, slot tid&3); global source
    // column is pre-swizzled so that LDS slot s of row rw holds global
    // quarter s ^ ((rw>>1)&3).
    int rw = tid >> 2;
    int kc = (((tid & 3) ^ ((rw >> 1) & 3)) << 3);
    const unsigned short* a0 = A + (size_t)(m0 + rw) * K + kc;
    const unsigned short* a1 = A + (size_t)(m0 + 128 + rw) * K + kc;  // (rw+128>>1)&3 == (rw>>1)&3
    const unsigned short* b0 = B + (size_t)(n0 + rw) * K + kc;
    const unsigned short* b1 = B + (size_t)(n0 + 128 + rw) * K + kc;

    // prologue: tiles 0,1,2 -> bufs 0,1,2 (group order matters for vmcnt)
#pragma unroll
    for (int t = 0; t < 3; ++t) {
        int ko = t * 32;
        async16(&As[t][wave * 512], a0 + ko);
        async16(&As[t][4096 + wave * 512], a1 + ko);
        async16(&Bs[t][wave * 512], b0 + ko);
        async16(&Bs[t][4096 + wave * 512], b1 + ko);
        __builtin_amdgcn_sched_barrier(0);
    }

    for (int it = 0; it < 32; ++it) {
        if (it < 30)       __builtin_amdgcn_s_waitcnt(WAIT_VM8);
        else if (it == 30) __builtin_amdgcn_s_waitcnt(WAIT_VM4);
        else               __builtin_amdgcn_s_waitcnt(WAIT_VM0);
        __builtin_amdgcn_s_barrier();
        __builtin_amdgcn_sched_barrier(0);

        int bc = it & 3;
        int bn = (it + 3) & 3;
        int ko = (it + 3) * 32;
        if (it + 3 < 32) {
            async16(&As[bn][wave * 512], a0 + ko);
            async16(&As[bn][4096 + wave * 512], a1 + ko);
            async16(&Bs[bn][wave * 512], b0 + ko);
            async16(&Bs[bn][4096 + wave * 512], b1 + ko);
        }

        bf16x8 af[8], bfr[4];
#pragma unroll
        for (int ni = 0; ni < 4; ni++)
            bfr[ni] = *(const bf16x8*)&Bs[bc][(wc * 64 + ni * 16 + r) * 32 + qs * 8];
#pragma unroll
        for (int mi = 0; mi < 8; mi++)
            af[mi] = *(const bf16x8*)&As[bc][(wr * 128 + mi * 16 + r) * 32 + qs * 8];

        __builtin_amdgcn_s_setprio(1);
#pragma unroll
        for (int mi = 0; mi < 8; mi++)
#pragma unroll
            for (int ni = 0; ni < 4; ni++)
                acc[mi][ni] = __builtin_amdgcn_mfma_f32_16x16x32_bf16(
                    af[mi], bfr[ni], acc[mi][ni], 0, 0, 0);
        __builtin_amdgcn_s_setprio(0);
        __builtin_amdgcn_sched_barrier(0);  // keep staging inside this iteration
    }
}

// Fused QKV projection: out[m][n] = sum_k x[m][k]*wqkv[n][k],
// M=8192, N=3072, K=1024. Grid 384 blocks (12 N-tiles x 32 M-tiles),
// XCD-chunked swizzle (384 % 8 == 0 -> bijective).
__global__ __launch_bounds__(512) void gemm_qkv(const unsigned short* __restrict__ A,
                                                const unsigned short* __restrict__ B,
                                                unsigned short* __restrict__ Qb,
                                                unsigned short* __restrict__ Kb,
                                                unsigned short* __restrict__ Vtb) {
    __shared__ unsigned short As[4][8192];  // [buf][256 rows x 32 k]
    __shared__ unsigned short Bs[4][8192];
    int id = blockIdx.x;
    int swz = (id & 7) * 48 + (id >> 3);
    int bx = swz % 12, by = swz / 12;
    int m0 = by * 256, n0 = bx * 256;

    f32x4 acc[8][4];
    gemm256_loop(A, B, m0, n0, As, Bs, acc);

    int tid = threadIdx.x;
    int wave = tid >> 6, lane = tid & 63;
    int r = lane & 15, q = lane >> 4;
    int wr = wave >> 2, wc = wave & 3;
#pragma unroll
    for (int mi = 0; mi < 8; mi++) {
#pragma unroll
        for (int ni = 0; ni < 4; ni++) {
#pragma unroll
            for (int rr = 0; rr < 4; rr++) {
                int gm = m0 + wr * 128 + mi * 16 + q * 4 + rr;
                int gn = n0 + wc * 64 + ni * 16 + r;
                float v = acc[mi][ni][rr];
                int b = gm >> 11, t = gm & 2047;
                int sel = gn >> 10, nn = gn & 1023;
                int h = nn >> 6, d = nn & 63;
                if (sel == 0)
                    Qb[((size_t)(b * 16 + h) * 2048 + t) * 64 + d] = f2bf(v);
                else if (sel == 1)
                    Kb[((size_t)(b * 16 + h) * 2048 + t) * 64 + d] = f2bf(v);
                else
                    Vtb[((size_t)(b * 16 + h) * 64 + d) * 2048 + t] = f2bf(v);
            }
        }
    }
}

// Final projection, same 256-tile K-loop, fp32 out. M=8192, N=1024, K=1024.
// Grid 128 blocks (4 N-tiles x 32 M-tiles), XCD swizzle (128 % 8 == 0).
__global__ __launch_bounds__(512) void gemm_out(const unsigned short* __restrict__ A,
                                                const unsigned short* __restrict__ B,
                                                float* __restrict__ out) {
    __shared__ unsigned short As[4][8192];
    __shared__ unsigned short Bs[4][8192];
    int id = blockIdx.x;
    int swz = (id & 7) * 16 + (id >> 3);
    int bx = swz & 3, by = swz >> 2;
    int m0 = by * 256, n0 = bx * 256;

    f32x4 acc[8][4];
    gemm256_loop(A, B, m0, n0, As, Bs, acc);

    int tid = threadIdx.x;
    int wave = tid >> 6, lane = tid & 63;
    int r = lane & 15, q = lane >> 4;
    int wr = wave >> 2, wc = wave & 3;
#pragma unroll
    for (int mi = 0; mi < 8; mi++)
#pragma unroll
        for (int ni = 0; ni < 4; ni++)
#pragma unroll
            for (int rr = 0; rr < 4; rr++) {
                int gm = m0 + wr * 128 + mi * 16 + q * 4 + rr;
                int gn = n0 + wc * 64 + ni * 16 + r;
                out[(size_t)gm * 1024 + gn] = acc[mi][ni][rr];
            }
}

// Suffix sums of V at 64-key granularity: SV[bh][j][d] = sum_{k >= 64j} V[bh][k][d]
__global__ __launch_bounds__(256) void suffix_sv(const unsigned short* __restrict__ Vt,
                                                 float* __restrict__ SV) {
    __shared__ float bsum[32][64];
    int bh = blockIdx.x;
    int d = threadIdx.x & 63, c = threadIdx.x >> 6;
    const unsigned short* base = Vt + ((size_t)bh * 64 + d) * T_SEQ;
#pragma unroll
    for (int jj = 0; jj < 8; jj++) {
        int j = c * 8 + jj;
        float s = 0.f;
#pragma unroll
        for (int t8 = 0; t8 < 8; t8++) {
            bf16x8 v = *(const bf16x8*)(base + j * 64 + t8 * 8);
#pragma unroll
            for (int e = 0; e < 8; e++) s += bf2f((unsigned short)v[e]);
        }
        bsum[j][d] = s;
    }
    __syncthreads();
    if (threadIdx.x < 64) {
        float run = 0.f;
        for (int j = 31; j >= 0; j--) {
            run += bsum[j][d];
            SV[((size_t)bh * 32 + j) * 64 + d] = run;
        }
    }
}

// Flash attention (R6 structure, unchanged): transposed-S, no-max softmax,
// analytic -10 tail, register-prefetch staging, 2-phase uniform load balance.
#define KST 72
#define VST 72
#define PST 72
__global__ __launch_bounds__(256) void attn(const unsigned short* __restrict__ Q,
                                            const unsigned short* __restrict__ Kg,
                                            const unsigned short* __restrict__ Vt,
                                            const float* __restrict__ SV,
                                            unsigned short* __restrict__ Y) {
    __shared__ unsigned short Ks[64 * KST];    // [key][d]
    __shared__ unsigned short Vs[64 * VST];    // [d][key]
    __shared__ unsigned short Ps[4][16 * PST]; // per wave: [query][key]
    int bh = blockIdx.y;
    int tid = threadIdx.x, wave = tid >> 6, lane = tid & 63;
    int r = lane & 15, qd = lane >> 4;
    int b = bh >> 4, h = bh & 15;

    int srow = tid >> 2, scol = (tid & 3) * 16;  // staging: 64 rows x 128B
    const unsigned short* kg = Kg + ((size_t)bh * T_SEQ + srow) * 64 + scol;
    const unsigned short* vg = Vt + ((size_t)bh * 64 + srow) * T_SEQ + scol;
    const float scale = 0.125f;

#pragma unroll
    for (int phase = 0; phase < 2; phase++) {
        int qi = phase == 0 ? 16 + (int)blockIdx.x : 15 - (int)blockIdx.x;
        int q0 = qi * 64;
        int query = q0 + wave * 16 + r;

        const unsigned short* qptr = Q + ((size_t)bh * T_SEQ + query) * 64 + qd * 8;
        bf16x8 qf0 = *(const bf16x8*)qptr;
        bf16x8 qf1 = *(const bf16x8*)(qptr + 32);

        float l_lane = 0.0f;
        f32x4 o[4];
#pragma unroll
        for (int n = 0; n < 4; n++) o[n] = (f32x4){0.f, 0.f, 0.f, 0.f};

        bf16x8 pk0 = *(const bf16x8*)(kg);
        bf16x8 pk1 = *(const bf16x8*)(kg + 8);
        bf16x8 pv0 = *(const bf16x8*)(vg);
        bf16x8 pv1 = *(const bf16x8*)(vg + 8);

        int iters = qi + 1;
        for (int it = 0; it < iters; ++it) {
            __syncthreads();
            *(bf16x8*)&Ks[srow * KST + scol]     = pk0;
            *(bf16x8*)&Ks[srow * KST + scol + 8] = pk1;
            *(bf16x8*)&Vs[srow * VST + scol]     = pv0;
            *(bf16x8*)&Vs[srow * VST + scol + 8] = pv1;
            __syncthreads();
            if (it + 1 < iters) {
                size_t kn = (size_t)(it + 1) * 64;
                pk0 = *(const bf16x8*)(kg + kn * 64);
                pk1 = *(const bf16x8*)(kg + kn * 64 + 8);
                pv0 = *(const bf16x8*)(vg + kn);
                pv1 = *(const bf16x8*)(vg + kn + 8);
            }

            int k0 = it * 64;
            f32x4 st[4];
#pragma unroll
            for (int t = 0; t < 4; t++) {
                bf16x8 kf0 = *(const bf16x8*)&Ks[(t * 16 + r) * KST + qd * 8];
                bf16x8 kf1 = *(const bf16x8*)&Ks[(t * 16 + r) * KST + 32 + qd * 8];
                st[t] = (f32x4){0.f, 0.f, 0.f, 0.f};
                st[t] = __builtin_amdgcn_mfma_f32_16x16x32_bf16(kf0, qf0, st[t], 0, 0, 0);
                st[t] = __builtin_amdgcn_mfma_f32_16x16x32_bf16(kf1, qf1, st[t], 0, 0, 0);
            }

            float p[4][4], sum = 0.f;
            bool anymask = (k0 + 63 > q0 + wave * 16);  // wave-uniform
            if (anymask) {
#pragma unroll
                for (int t = 0; t < 4; t++)
#pragma unroll
                    for (int e = 0; e < 4; e++) {
                        int kgidx = k0 + t * 16 + qd * 4 + e;
                        float pe = __expf(st[t][e] * scale);
                        p[t][e] = (kgidx <= query) ? pe : EXPM10;
                        sum += p[t][e];
                    }
            } else {
#pragma unroll
                for (int t = 0; t < 4; t++)
#pragma unroll
                    for (int e = 0; e < 4; e++) {
                        p[t][e] = __expf(st[t][e] * scale);
                        sum += p[t][e];
                    }
            }
            l_lane += sum;

#pragma unroll
            for (int t = 0; t < 4; t++) {
                ushort4 pk;
                pk.x = f2bf(p[t][0]); pk.y = f2bf(p[t][1]);
                pk.z = f2bf(p[t][2]); pk.w = f2bf(p[t][3]);
                *(ushort4*)&Ps[wave][r * PST + t * 16 + qd * 4] = pk;
            }
            __builtin_amdgcn_sched_barrier(0);  // wave-private Ps: keep order

            bf16x8 pf0 = *(const bf16x8*)&Ps[wave][r * PST + qd * 8];
            bf16x8 pf1 = *(const bf16x8*)&Ps[wave][r * PST + 32 + qd * 8];
#pragma unroll
            for (int n = 0; n < 4; n++) {
                bf16x8 vf0 = *(const bf16x8*)&Vs[(n * 16 + r) * VST + qd * 8];
                bf16x8 vf1 = *(const bf16x8*)&Vs[(n * 16 + r) * VST + 32 + qd * 8];
                o[n] = __builtin_amdgcn_mfma_f32_16x16x32_bf16(vf0, pf0, o[n], 0, 0, 0);
                o[n] = __builtin_amdgcn_mfma_f32_16x16x32_bf16(vf1, pf1, o[n], 0, 0, 0);
            }
        }

        float l_i = l_lane;
        l_i += __shfl_xor(l_i, 16);
        l_i += __shfl_xor(l_i, 32);

        int j = qi + 1;
        float pm = 0.f, tail_l = 0.f;
        float sv[4][4];
#pragma unroll
        for (int n = 0; n < 4; n++)
#pragma unroll
            for (int e = 0; e < 4; e++) sv[n][e] = 0.f;
        if (j < 32) {
            pm = EXPM10;
            tail_l = (float)(T_SEQ - 64 * j) * pm;
            const float* svp = SV + ((size_t)bh * 32 + j) * 64;
#pragma unroll
            for (int n = 0; n < 4; n++) {
                float4 f = *(const float4*)(svp + n * 16 + qd * 4);
                sv[n][0] = f.x; sv[n][1] = f.y; sv[n][2] = f.z; sv[n][3] = f.w;
            }
        }
        float inv = 1.0f / (l_i + tail_l);
#pragma unroll
        for (int n = 0; n < 4; n++) {
            ushort4 yk;
            yk.x = f2bf((o[n][0] + pm * sv[n][0]) * inv);
            yk.y = f2bf((o[n][1] + pm * sv[n][1]) * inv);
            yk.z = f2bf((o[n][2] + pm * sv[n][2]) * inv);
            yk.w = f2bf((o[n][3] + pm * sv[n][3]) * inv);
            *(ushort4*)&Y[(((size_t)b * T_SEQ + query) * 16 + h) * 64 + n * 16 + qd * 4] = yk;
        }
    }
}

extern "C" void kernel_launch(void* const* d_in, const int* in_sizes, int n_in,
                              void* d_out, int out_size, void* d_ws, size_t ws_size,
                              hipStream_t stream) {
    const float* x  = (const float*)d_in[0];
    const float* wq = (const float*)d_in[1];
    const float* wk = (const float*)d_in[2];
    const float* wv = (const float*)d_in[3];
    const float* wo = (const float*)d_in[4];

    char* ws = (char*)d_ws;
    const size_t MB = 1u << 20;
    unsigned short* xb   = (unsigned short*)(ws);            // 16 MB (reused as Yb)
    unsigned short* Qb   = (unsigned short*)(ws + 16 * MB);  // 16 MB
    unsigned short* Kb   = (unsigned short*)(ws + 32 * MB);  // 16 MB
    unsigned short* Vtb  = (unsigned short*)(ws + 48 * MB);  // 16 MB
    unsigned short* wqkv = (unsigned short*)(ws + 64 * MB);  // 6 MB
    unsigned short* wob  = (unsigned short*)(ws + 70 * MB);  // 2 MB -> 72 MB total
    unsigned short* Yb   = xb;
    float* SVf = (float*)d_out;  // scratch until final gemm overwrites d_out

    cvt_bf16<<<8192, 256, 0, stream>>>(x, xb, 2097152);
    cvt_w<<<4096, 256, 0, stream>>>(wq, wk, wv, wo, wqkv, wob);

    gemm_qkv<<<384, 512, 0, stream>>>(xb, wqkv, Qb, Kb, Vtb);

    suffix_sv<<<64, 256, 0, stream>>>(Vtb, SVf);

    attn<<<dim3(16, 64), 256, 0, stream>>>(Qb, Kb, Vtb, SVf, Yb);

    gemm_out<<<128, 512, 0, stream>>>(Yb, wob, (float*)d_out);
}

// Round 7
// 306.688 us; speedup vs baseline: 1.0680x; 1.0680x over previous
//
#include <hip/hip_runtime.h>

typedef __attribute__((ext_vector_type(8))) short bf16x8;
typedef __attribute__((ext_vector_type(4))) float f32x4;

#define T_SEQ 2048
#define EXPM10 4.5399929762484854e-05f  // exp(-10)

// s_waitcnt imm (gfx9 encoding): vmcnt[3:0] | expcnt<<4 | lgkmcnt<<8
#define WAIT_VM8 0xF78  // vmcnt(8)
#define WAIT_VM0 0xF70  // vmcnt(0)

__device__ __forceinline__ unsigned short f2bf(float f) {
    unsigned int u = __builtin_bit_cast(unsigned int, f);
    u += 0x7fffu + ((u >> 16) & 1u);
    return (unsigned short)(u >> 16);
}
__device__ __forceinline__ float bf2f(unsigned short u) {
    return __builtin_bit_cast(float, (unsigned int)u << 16);
}

__device__ __forceinline__ void async16(void* lds, const void* g) {
    __builtin_amdgcn_global_load_lds(
        (__attribute__((address_space(1))) void*)g,
        (__attribute__((address_space(3))) void*)lds, 16, 0, 0);
}

// fp32 -> bf16, 4 elems/thread (x activation)
__global__ __launch_bounds__(256) void cvt_bf16(const float* __restrict__ src,
                                                unsigned short* __restrict__ dst, int n4) {
    int i = blockIdx.x * 256 + threadIdx.x;
    if (i < n4) {
        float4 v = ((const float4*)src)[i];
        ushort4 r;
        r.x = f2bf(v.x); r.y = f2bf(v.y); r.z = f2bf(v.z); r.w = f2bf(v.w);
        ((ushort4*)dst)[i] = r;
    }
}

// all 4 weight matrices in one dispatch: wq/wk/wv -> contiguous wqkv, wo -> wob
__global__ __launch_bounds__(256) void cvt_w(const float* __restrict__ wq,
                                             const float* __restrict__ wk,
                                             const float* __restrict__ wv,
                                             const float* __restrict__ wo,
                                             unsigned short* __restrict__ wqkv,
                                             unsigned short* __restrict__ wob) {
    int which = blockIdx.x >> 10;
    int i = (blockIdx.x & 1023) * 256 + threadIdx.x;
    const float* src = which == 0 ? wq : which == 1 ? wk : which == 2 ? wv : wo;
    unsigned short* dst = which < 3 ? wqkv + (size_t)which * 1048576 : wob;
    float4 v = ((const float4*)src)[i];
    ushort4 r;
    r.x = f2bf(v.x); r.y = f2bf(v.y); r.z = f2bf(v.z); r.w = f2bf(v.w);
    ((ushort4*)dst)[i] = r;
}

// R6 GEMM core: 128x128 tile, 4 waves (2x2), BK=64, double-buffered 64KB LDS
// -> 2 blocks/CU resident (acc 64 AGPR + ~70 VGPR fits 3 waves/SIMD).
// R1-proven 2-barrier schedule, but 2x the K-depth per sync:
//   barrier1; stage tile it+1 (8 x global_load_lds, pre-swizzled source);
//   vmcnt(8) [own tile-it loads landed, it+1 stays in flight]; barrier2;
//   unfenced {16 ds_read_b128 + 32 MFMA} (compiler emits counted lgkmcnt).
// Cross-block overlap (2 blocks/CU) fills the vmcnt/barrier bubbles that
// capped the 1-block 256-tile versions (R4/R5) at MfmaUtil 17-20%.
// LDS swizzle (measured 0 conflicts in R5): row = 128B = 8 x 16B slots;
// stored slot j holds global chunk j ^ (row&7). Stage side pre-swizzles the
// GLOBAL column (global_load_lds LDS dest must stay linear); read side
// applies the same XOR. 8 lanes per 4-bank group = balanced floor.
__device__ __forceinline__ void gemm128_loop(const unsigned short* __restrict__ A,
                                             const unsigned short* __restrict__ B,
                                             int m0, int n0,
                                             unsigned short (*As)[8192],
                                             unsigned short (*Bs)[8192],
                                             f32x4 acc[4][4]) {
    const int K = 1024;
    int tid = threadIdx.x;
    int wave = tid >> 6, lane = tid & 63;
    int r = lane & 15, q = lane >> 4;
    int wr = wave >> 1, wc = wave & 1;

#pragma unroll
    for (int i = 0; i < 4; i++)
#pragma unroll
        for (int j = 0; j < 4; j++) acc[i][j] = (f32x4){0.f, 0.f, 0.f, 0.f};

    // staging: chunk c = i*256 + tid (i=0..3), row = c>>3, slot = c&7,
    // global col chunk = slot ^ (row&7). (i*32 ≡ 0 mod 8 -> same gcol all i.)
    int srow = tid >> 3;
    int gcol = (((tid & 7) ^ (srow & 7)) << 3);
    const unsigned short* ap[4];
    const unsigned short* bp[4];
#pragma unroll
    for (int i = 0; i < 4; i++) {
        ap[i] = A + (size_t)(m0 + i * 32 + srow) * K + gcol;
        bp[i] = B + (size_t)(n0 + i * 32 + srow) * K + gcol;
    }

    // read-side swizzled slots (shorts): row&7 == r&7 for all fragment rows
    int sl0 = ((q ^ (r & 7)) << 3);        // k-sub 0: chunks 0..3
    int sl1 = (((4 | q) ^ (r & 7)) << 3);  // k-sub 1: chunks 4..7
    int rA = wr * 64 + r;
    int rB = wc * 64 + r;

    // prologue: tile 0 -> buf 0
#pragma unroll
    for (int i = 0; i < 4; i++) async16(&As[0][i * 2048 + wave * 512], ap[i]);
#pragma unroll
    for (int i = 0; i < 4; i++) async16(&Bs[0][i * 2048 + wave * 512], bp[i]);
    __builtin_amdgcn_sched_barrier(0);

    for (int it = 0; it < 16; ++it) {
        __builtin_amdgcn_s_barrier();  // buf[(it+1)&1] readers (iter it-1) done
        __builtin_amdgcn_sched_barrier(0);
        if (it + 1 < 16) {
            int bn = (it + 1) & 1;
            int ko = (it + 1) * 64;
#pragma unroll
            for (int i = 0; i < 4; i++) async16(&As[bn][i * 2048 + wave * 512], ap[i] + ko);
#pragma unroll
            for (int i = 0; i < 4; i++) async16(&Bs[bn][i * 2048 + wave * 512], bp[i] + ko);
            __builtin_amdgcn_sched_barrier(0);
            __builtin_amdgcn_s_waitcnt(WAIT_VM8);  // tile-it landed, it+1 in flight
        } else {
            __builtin_amdgcn_s_waitcnt(WAIT_VM0);
        }
        __builtin_amdgcn_s_barrier();  // whole tile resident
        __builtin_amdgcn_sched_barrier(0);

        int bc = it & 1;
        bf16x8 af0[4], af1[4], bf0[4], bf1[4];
#pragma unroll
        for (int mi = 0; mi < 4; mi++) {
            af0[mi] = *(const bf16x8*)&As[bc][(rA + mi * 16) * 64 + sl0];
            af1[mi] = *(const bf16x8*)&As[bc][(rA + mi * 16) * 64 + sl1];
        }
#pragma unroll
        for (int ni = 0; ni < 4; ni++) {
            bf0[ni] = *(const bf16x8*)&Bs[bc][(rB + ni * 16) * 64 + sl0];
            bf1[ni] = *(const bf16x8*)&Bs[bc][(rB + ni * 16) * 64 + sl1];
        }
        __builtin_amdgcn_s_setprio(1);
#pragma unroll
        for (int mi = 0; mi < 4; mi++)
#pragma unroll
            for (int ni = 0; ni < 4; ni++)
                acc[mi][ni] = __builtin_amdgcn_mfma_f32_16x16x32_bf16(
                    af0[mi], bf0[ni], acc[mi][ni], 0, 0, 0);
#pragma unroll
        for (int mi = 0; mi < 4; mi++)
#pragma unroll
            for (int ni = 0; ni < 4; ni++)
                acc[mi][ni] = __builtin_amdgcn_mfma_f32_16x16x32_bf16(
                    af1[mi], bf1[ni], acc[mi][ni], 0, 0, 0);
        __builtin_amdgcn_s_setprio(0);
        __builtin_amdgcn_sched_barrier(0);
    }
}

// Fused QKV projection: out[m][n] = sum_k x[m][k]*wqkv[n][k],
// M=8192, N=3072, K=1024. Grid 1536 blocks (24 N-tiles x 64 M-tiles),
// column-major linearization + XCD-chunked swizzle (1536 % 8 == 0) so each
// XCD keeps its B panels (256KB each) resident in its private L2.
__global__ __launch_bounds__(256) void gemm_qkv(const unsigned short* __restrict__ A,
                                                const unsigned short* __restrict__ B,
                                                unsigned short* __restrict__ Qb,
                                                unsigned short* __restrict__ Kb,
                                                unsigned short* __restrict__ Vtb) {
    __shared__ unsigned short As[2][8192];  // [buf][128 rows x 64 k]
    __shared__ unsigned short Bs[2][8192];
    int id = blockIdx.x;
    int swz = (id & 7) * 192 + (id >> 3);
    int bx = swz >> 6, by = swz & 63;  // swz = bx*64 + by
    int m0 = by * 128, n0 = bx * 128;

    f32x4 acc[4][4];
    gemm128_loop(A, B, m0, n0, As, Bs, acc);

    int tid = threadIdx.x;
    int wave = tid >> 6, lane = tid & 63;
    int r = lane & 15, q = lane >> 4;
    int wr = wave >> 1, wc = wave & 1;
#pragma unroll
    for (int mi = 0; mi < 4; mi++) {
#pragma unroll
        for (int ni = 0; ni < 4; ni++) {
#pragma unroll
            for (int rr = 0; rr < 4; rr++) {
                int gm = m0 + wr * 64 + mi * 16 + q * 4 + rr;
                int gn = n0 + wc * 64 + ni * 16 + r;
                float v = acc[mi][ni][rr];
                int b = gm >> 11, t = gm & 2047;
                int sel = gn >> 10, nn = gn & 1023;
                int h = nn >> 6, d = nn & 63;
                if (sel == 0)
                    Qb[((size_t)(b * 16 + h) * 2048 + t) * 64 + d] = f2bf(v);
                else if (sel == 1)
                    Kb[((size_t)(b * 16 + h) * 2048 + t) * 64 + d] = f2bf(v);
                else
                    Vtb[((size_t)(b * 16 + h) * 64 + d) * 2048 + t] = f2bf(v);
            }
        }
    }
}

// Final projection, same core, fp32 out. M=8192, N=1024, K=1024.
// Grid 512 blocks (8 N-tiles x 64 M-tiles), col-major + XCD swizzle.
__global__ __launch_bounds__(256) void gemm_out(const unsigned short* __restrict__ A,
                                                const unsigned short* __restrict__ B,
                                                float* __restrict__ out) {
    __shared__ unsigned short As[2][8192];
    __shared__ unsigned short Bs[2][8192];
    int id = blockIdx.x;
    int swz = (id & 7) * 64 + (id >> 3);
    int bx = swz >> 6, by = swz & 63;
    int m0 = by * 128, n0 = bx * 128;

    f32x4 acc[4][4];
    gemm128_loop(A, B, m0, n0, As, Bs, acc);

    int tid = threadIdx.x;
    int wave = tid >> 6, lane = tid & 63;
    int r = lane & 15, q = lane >> 4;
    int wr = wave >> 1, wc = wave & 1;
#pragma unroll
    for (int mi = 0; mi < 4; mi++)
#pragma unroll
        for (int ni = 0; ni < 4; ni++)
#pragma unroll
            for (int rr = 0; rr < 4; rr++) {
                int gm = m0 + wr * 64 + mi * 16 + q * 4 + rr;
                int gn = n0 + wc * 64 + ni * 16 + r;
                out[(size_t)gm * 1024 + gn] = acc[mi][ni][rr];
            }
}

// Suffix sums of V at 64-key granularity: SV[bh][j][d] = sum_{k >= 64j} V[bh][k][d]
__global__ __launch_bounds__(256) void suffix_sv(const unsigned short* __restrict__ Vt,
                                                 float* __restrict__ SV) {
    __shared__ float bsum[32][64];
    int bh = blockIdx.x;
    int d = threadIdx.x & 63, c = threadIdx.x >> 6;
    const unsigned short* base = Vt + ((size_t)bh * 64 + d) * T_SEQ;
#pragma unroll
    for (int jj = 0; jj < 8; jj++) {
        int j = c * 8 + jj;
        float s = 0.f;
#pragma unroll
        for (int t8 = 0; t8 < 8; t8++) {
            bf16x8 v = *(const bf16x8*)(base + j * 64 + t8 * 8);
#pragma unroll
            for (int e = 0; e < 8; e++) s += bf2f((unsigned short)v[e]);
        }
        bsum[j][d] = s;
    }
    __syncthreads();
    if (threadIdx.x < 64) {
        float run = 0.f;
        for (int j = 31; j >= 0; j--) {
            run += bsum[j][d];
            SV[((size_t)bh * 32 + j) * 64 + d] = run;
        }
    }
}

// Flash attention (R6 structure, unchanged): transposed-S, no-max softmax,
// analytic -10 tail, register-prefetch staging, 2-phase uniform load balance.
#define KST 72
#define VST 72
#define PST 72
__global__ __launch_bounds__(256) void attn(const unsigned short* __restrict__ Q,
                                            const unsigned short* __restrict__ Kg,
                                            const unsigned short* __restrict__ Vt,
                                            const float* __restrict__ SV,
                                            unsigned short* __restrict__ Y) {
    __shared__ unsigned short Ks[64 * KST];    // [key][d]
    __shared__ unsigned short Vs[64 * VST];    // [d][key]
    __shared__ unsigned short Ps[4][16 * PST]; // per wave: [query][key]
    int bh = blockIdx.y;
    int tid = threadIdx.x, wave = tid >> 6, lane = tid & 63;
    int r = lane & 15, qd = lane >> 4;
    int b = bh >> 4, h = bh & 15;

    int srow = tid >> 2, scol = (tid & 3) * 16;  // staging: 64 rows x 128B
    const unsigned short* kg = Kg + ((size_t)bh * T_SEQ + srow) * 64 + scol;
    const unsigned short* vg = Vt + ((size_t)bh * 64 + srow) * T_SEQ + scol;
    const float scale = 0.125f;

#pragma unroll
    for (int phase = 0; phase < 2; phase++) {
        int qi = phase == 0 ? 16 + (int)blockIdx.x : 15 - (int)blockIdx.x;
        int q0 = qi * 64;
        int query = q0 + wave * 16 + r;

        const unsigned short* qptr = Q + ((size_t)bh * T_SEQ + query) * 64 + qd * 8;
        bf16x8 qf0 = *(const bf16x8*)qptr;
        bf16x8 qf1 = *(const bf16x8*)(qptr + 32);

        float l_lane = 0.0f;
        f32x4 o[4];
#pragma unroll
        for (int n = 0; n < 4; n++) o[n] = (f32x4){0.f, 0.f, 0.f, 0.f};

        bf16x8 pk0 = *(const bf16x8*)(kg);
        bf16x8 pk1 = *(const bf16x8*)(kg + 8);
        bf16x8 pv0 = *(const bf16x8*)(vg);
        bf16x8 pv1 = *(const bf16x8*)(vg + 8);

        int iters = qi + 1;
        for (int it = 0; it < iters; ++it) {
            __syncthreads();
            *(bf16x8*)&Ks[srow * KST + scol]     = pk0;
            *(bf16x8*)&Ks[srow * KST + scol + 8] = pk1;
            *(bf16x8*)&Vs[srow * VST + scol]     = pv0;
            *(bf16x8*)&Vs[srow * VST + scol + 8] = pv1;
            __syncthreads();
            if (it + 1 < iters) {
                size_t kn = (size_t)(it + 1) * 64;
                pk0 = *(const bf16x8*)(kg + kn * 64);
                pk1 = *(const bf16x8*)(kg + kn * 64 + 8);
                pv0 = *(const bf16x8*)(vg + kn);
                pv1 = *(const bf16x8*)(vg + kn + 8);
            }

            int k0 = it * 64;
            f32x4 st[4];
#pragma unroll
            for (int t = 0; t < 4; t++) {
                bf16x8 kf0 = *(const bf16x8*)&Ks[(t * 16 + r) * KST + qd * 8];
                bf16x8 kf1 = *(const bf16x8*)&Ks[(t * 16 + r) * KST + 32 + qd * 8];
                st[t] = (f32x4){0.f, 0.f, 0.f, 0.f};
                st[t] = __builtin_amdgcn_mfma_f32_16x16x32_bf16(kf0, qf0, st[t], 0, 0, 0);
                st[t] = __builtin_amdgcn_mfma_f32_16x16x32_bf16(kf1, qf1, st[t], 0, 0, 0);
            }

            float p[4][4], sum = 0.f;
            bool anymask = (k0 + 63 > q0 + wave * 16);  // wave-uniform
            if (anymask) {
#pragma unroll
                for (int t = 0; t < 4; t++)
#pragma unroll
                    for (int e = 0; e < 4; e++) {
                        int kgidx = k0 + t * 16 + qd * 4 + e;
                        float pe = __expf(st[t][e] * scale);
                        p[t][e] = (kgidx <= query) ? pe : EXPM10;
                        sum += p[t][e];
                    }
            } else {
#pragma unroll
                for (int t = 0; t < 4; t++)
#pragma unroll
                    for (int e = 0; e < 4; e++) {
                        p[t][e] = __expf(st[t][e] * scale);
                        sum += p[t][e];
                    }
            }
            l_lane += sum;

#pragma unroll
            for (int t = 0; t < 4; t++) {
                ushort4 pk;
                pk.x = f2bf(p[t][0]); pk.y = f2bf(p[t][1]);
                pk.z = f2bf(p[t][2]); pk.w = f2bf(p[t][3]);
                *(ushort4*)&Ps[wave][r * PST + t * 16 + qd * 4] = pk;
            }
            __builtin_amdgcn_sched_barrier(0);  // wave-private Ps: keep order

            bf16x8 pf0 = *(const bf16x8*)&Ps[wave][r * PST + qd * 8];
            bf16x8 pf1 = *(const bf16x8*)&Ps[wave][r * PST + 32 + qd * 8];
#pragma unroll
            for (int n = 0; n < 4; n++) {
                bf16x8 vf0 = *(const bf16x8*)&Vs[(n * 16 + r) * VST + qd * 8];
                bf16x8 vf1 = *(const bf16x8*)&Vs[(n * 16 + r) * VST + 32 + qd * 8];
                o[n] = __builtin_amdgcn_mfma_f32_16x16x32_bf16(vf0, pf0, o[n], 0, 0, 0);
                o[n] = __builtin_amdgcn_mfma_f32_16x16x32_bf16(vf1, pf1, o[n], 0, 0, 0);
            }
        }

        float l_i = l_lane;
        l_i += __shfl_xor(l_i, 16);
        l_i += __shfl_xor(l_i, 32);

        int j = qi + 1;
        float pm = 0.f, tail_l = 0.f;
        float sv[4][4];
#pragma unroll
        for (int n = 0; n < 4; n++)
#pragma unroll
            for (int e = 0; e < 4; e++) sv[n][e] = 0.f;
        if (j < 32) {
            pm = EXPM10;
            tail_l = (float)(T_SEQ - 64 * j) * pm;
            const float* svp = SV + ((size_t)bh * 32 + j) * 64;
#pragma unroll
            for (int n = 0; n < 4; n++) {
                float4 f = *(const float4*)(svp + n * 16 + qd * 4);
                sv[n][0] = f.x; sv[n][1] = f.y; sv[n][2] = f.z; sv[n][3] = f.w;
            }
        }
        float inv = 1.0f / (l_i + tail_l);
#pragma unroll
        for (int n = 0; n < 4; n++) {
            ushort4 yk;
            yk.x = f2bf((o[n][0] + pm * sv[n][0]) * inv);
            yk.y = f2bf((o[n][1] + pm * sv[n][1]) * inv);
            yk.z = f2bf((o[n][2] + pm * sv[n][2]) * inv);
            yk.w = f2bf((o[n][3] + pm * sv[n][3]) * inv);
            *(ushort4*)&Y[(((size_t)b * T_SEQ + query) * 16 + h) * 64 + n * 16 + qd * 4] = yk;
        }
    }
}

extern "C" void kernel_launch(void* const* d_in, const int* in_sizes, int n_in,
                              void* d_out, int out_size, void* d_ws, size_t ws_size,
                              hipStream_t stream) {
    const float* x  = (const float*)d_in[0];
    const float* wq = (const float*)d_in[1];
    const float* wk = (const float*)d_in[2];
    const float* wv = (const float*)d_in[3];
    const float* wo = (const float*)d_in[4];

    char* ws = (char*)d_ws;
    const size_t MB = 1u << 20;
    unsigned short* xb   = (unsigned short*)(ws);            // 16 MB (reused as Yb)
    unsigned short* Qb   = (unsigned short*)(ws + 16 * MB);  // 16 MB
    unsigned short* Kb   = (unsigned short*)(ws + 32 * MB);  // 16 MB
    unsigned short* Vtb  = (unsigned short*)(ws + 48 * MB);  // 16 MB
    unsigned short* wqkv = (unsigned short*)(ws + 64 * MB);  // 6 MB
    unsigned short* wob  = (unsigned short*)(ws + 70 * MB);  // 2 MB -> 72 MB total
    unsigned short* Yb   = xb;
    float* SVf = (float*)d_out;  // scratch until final gemm overwrites d_out

    cvt_bf16<<<8192, 256, 0, stream>>>(x, xb, 2097152);
    cvt_w<<<4096, 256, 0, stream>>>(wq, wk, wv, wo, wqkv, wob);

    gemm_qkv<<<1536, 256, 0, stream>>>(xb, wqkv, Qb, Kb, Vtb);

    suffix_sv<<<64, 256, 0, stream>>>(Vtb, SVf);

    attn<<<dim3(16, 64), 256, 0, stream>>>(Qb, Kb, Vtb, SVf, Yb);

    gemm_out<<<512, 256, 0, stream>>>(Yb, wob, (float*)d_out);
}

// Round 8
// 297.053 us; speedup vs baseline: 1.1027x; 1.0324x over previous
//
#include <hip/hip_runtime.h>

typedef __attribute__((ext_vector_type(8))) short bf16x8;
typedef __attribute__((ext_vector_type(4))) float f32x4;

#define T_SEQ 2048
#define EXPM10 4.5399929762484854e-05f  // exp(-10)

// s_waitcnt imm (gfx9 encoding): vmcnt[3:0] | expcnt<<4 | lgkmcnt<<8
#define WAIT_VM3 0xF73  // vmcnt(3)
#define WAIT_VM0 0xF70  // vmcnt(0)

__device__ __forceinline__ unsigned short f2bf(float f) {
    unsigned int u = __builtin_bit_cast(unsigned int, f);
    u += 0x7fffu + ((u >> 16) & 1u);
    return (unsigned short)(u >> 16);
}
__device__ __forceinline__ float bf2f(unsigned short u) {
    return __builtin_bit_cast(float, (unsigned int)u << 16);
}

__device__ __forceinline__ void async16(void* lds, const void* g) {
    __builtin_amdgcn_global_load_lds(
        (__attribute__((address_space(1))) void*)g,
        (__attribute__((address_space(3))) void*)lds, 16, 0, 0);
}

// fp32 -> bf16, 4 elems/thread (x activation)
__global__ __launch_bounds__(256) void cvt_bf16(const float* __restrict__ src,
                                                unsigned short* __restrict__ dst, int n4) {
    int i = blockIdx.x * 256 + threadIdx.x;
    if (i < n4) {
        float4 v = ((const float4*)src)[i];
        ushort4 r;
        r.x = f2bf(v.x); r.y = f2bf(v.y); r.z = f2bf(v.z); r.w = f2bf(v.w);
        ((ushort4*)dst)[i] = r;
    }
}

// all 4 weight matrices in one dispatch: wq/wk/wv -> contiguous wqkv, wo -> wob
__global__ __launch_bounds__(256) void cvt_w(const float* __restrict__ wq,
                                             const float* __restrict__ wk,
                                             const float* __restrict__ wv,
                                             const float* __restrict__ wo,
                                             unsigned short* __restrict__ wqkv,
                                             unsigned short* __restrict__ wob) {
    int which = blockIdx.x >> 10;
    int i = (blockIdx.x & 1023) * 256 + threadIdx.x;
    const float* src = which == 0 ? wq : which == 1 ? wk : which == 2 ? wv : wo;
    unsigned short* dst = which < 3 ? wqkv + (size_t)which * 1048576 : wob;
    float4 v = ((const float4*)src)[i];
    ushort4 r;
    r.x = f2bf(v.x); r.y = f2bf(v.y); r.z = f2bf(v.z); r.w = f2bf(v.w);
    ((ushort4*)dst)[i] = r;
}

// R8 GEMM core: 256x128 tile, 512 threads (8 waves as 4M x 2N), BK=32,
// 3 LDS buffers (72 KB -> 2 blocks/CU), depth-2 counted vmcnt(3).
// Per K-step (template role-split schedule):
//   vmcnt(3)   -- own tile-it loads landed (tile it+1's 3 stay in flight)
//   barrier B1 -- tile it globally resident; buf[(it+2)%3] globally dead
//                 (its last ds_reads finished before each wave's previous
//                  MFMA band, hence before B1)
//   ds_read 8 frags (bc) ; stage tile it+2 (3 x global_load_lds -> bn)
//   barrier B2 -- all waves issued reads+stages before the MFMA band
//   setprio(1); 16 MFMA; setprio(0)
// Per wave: 16 MFMA / 8 ds_read / K-step (R1's proven ratio) but staged
// bytes per MFMA-flop cut 2.7x (24 KB/step over 8 waves vs 32 KB over 4),
// 2 blocks/CU cross-overlap + intra-block role-split, row-major block
// order (R1's proven L2 behavior; R7's col-major tripled FETCH).
// LDS swizzle (measured 0 conflicts): row = 64B = 4 x 16B slots; stored
// slot s of row R holds global chunk s ^ (R&3); stage side pre-swizzles
// the GLOBAL column (LDS dest of global_load_lds stays linear); read side
// applies the same XOR -> 32 distinct 16B granules per half-wave, 2-way
// aliasing only (free).
__device__ __forceinline__ void gemm_hp(const unsigned short* __restrict__ A,
                                        const unsigned short* __restrict__ B,
                                        int m0, int n0,
                                        unsigned short (*As)[8192],
                                        unsigned short (*Bs)[4096],
                                        f32x4 acc[4][4]) {
    const int K = 1024;
    int tid = threadIdx.x;
    int wave = tid >> 6, lane = tid & 63;
    int r = lane & 15, q = lane >> 4;
    int wr = wave >> 1, wc = wave & 1;

#pragma unroll
    for (int i = 0; i < 4; i++)
#pragma unroll
        for (int j = 0; j < 4; j++) acc[i][j] = (f32x4){0.f, 0.f, 0.f, 0.f};

    // staging: thread t covers LDS bytes [t*16, t*16+16): row t>>2, slot t&3.
    // global chunk = slot ^ (row&3); rows +128 are congruent mod 4.
    int rstg = tid >> 2;
    int gcol = (((tid & 3) ^ (rstg & 3)) << 3);
    const unsigned short* a0 = A + (size_t)(m0 + rstg) * K + gcol;        // A rows 0..127
    const unsigned short* a1 = A + (size_t)(m0 + 128 + rstg) * K + gcol;  // A rows 128..255
    const unsigned short* b0 = B + (size_t)(n0 + rstg) * K + gcol;        // B rows 0..127

    int slot = ((q ^ (r & 3)) << 3);  // read-side swizzled slot (shorts)
    int rA = wr * 64 + r;
    int rB = wc * 64 + r;

    // prologue: tiles 0,1 -> bufs 0,1 (3 loads each, tile-major order)
#pragma unroll
    for (int t = 0; t < 2; ++t) {
        async16(&As[t][tid * 8], a0 + t * 32);
        async16(&As[t][4096 + tid * 8], a1 + t * 32);
        async16(&Bs[t][tid * 8], b0 + t * 32);
        __builtin_amdgcn_sched_barrier(0);
    }

    int bc = 0, bn = 2;
    for (int it = 0; it < 32; ++it) {
        if (it < 31) __builtin_amdgcn_s_waitcnt(WAIT_VM3);
        else         __builtin_amdgcn_s_waitcnt(WAIT_VM0);
        __builtin_amdgcn_s_barrier();  // B1
        __builtin_amdgcn_sched_barrier(0);

        bf16x8 af[4], bfr[4];
#pragma unroll
        for (int mi = 0; mi < 4; mi++)
            af[mi] = *(const bf16x8*)&As[bc][(rA + mi * 16) * 32 + slot];
#pragma unroll
        for (int ni = 0; ni < 4; ni++)
            bfr[ni] = *(const bf16x8*)&Bs[bc][(rB + ni * 16) * 32 + slot];
        if (it + 2 < 32) {
            int ko = (it + 2) * 32;
            async16(&As[bn][tid * 8], a0 + ko);
            async16(&As[bn][4096 + tid * 8], a1 + ko);
            async16(&Bs[bn][tid * 8], b0 + ko);
        }
        __builtin_amdgcn_sched_barrier(0);
        __builtin_amdgcn_s_barrier();  // B2: role-split alignment
        __builtin_amdgcn_sched_barrier(0);

        __builtin_amdgcn_s_setprio(1);
#pragma unroll
        for (int mi = 0; mi < 4; mi++)
#pragma unroll
            for (int ni = 0; ni < 4; ni++)
                acc[mi][ni] = __builtin_amdgcn_mfma_f32_16x16x32_bf16(
                    af[mi], bfr[ni], acc[mi][ni], 0, 0, 0);
        __builtin_amdgcn_s_setprio(0);
        __builtin_amdgcn_sched_barrier(0);

        bc = bc == 2 ? 0 : bc + 1;
        bn = bn == 2 ? 0 : bn + 1;
    }
}

// Fused QKV projection: out[m][n] = sum_k x[m][k]*wqkv[n][k],
// M=8192, N=3072, K=1024. Grid 768 blocks (24 n-tiles x 32 m-tiles),
// row-major order (consecutive ids share the A-panel, R1-proven).
__global__ __launch_bounds__(512, 4) void gemm_qkv(const unsigned short* __restrict__ A,
                                                   const unsigned short* __restrict__ B,
                                                   unsigned short* __restrict__ Qb,
                                                   unsigned short* __restrict__ Kb,
                                                   unsigned short* __restrict__ Vtb) {
    __shared__ unsigned short As[3][8192];  // [buf][256 rows x 32 k]
    __shared__ unsigned short Bs[3][4096];  // [buf][128 rows x 32 k]
    int id = blockIdx.x;
    int bx = id % 24, by = id / 24;
    int m0 = by * 256, n0 = bx * 128;

    f32x4 acc[4][4];
    gemm_hp(A, B, m0, n0, As, Bs, acc);

    int tid = threadIdx.x;
    int wave = tid >> 6, lane = tid & 63;
    int r = lane & 15, q = lane >> 4;
    int wr = wave >> 1, wc = wave & 1;
#pragma unroll
    for (int mi = 0; mi < 4; mi++) {
#pragma unroll
        for (int ni = 0; ni < 4; ni++) {
#pragma unroll
            for (int rr = 0; rr < 4; rr++) {
                int gm = m0 + wr * 64 + mi * 16 + q * 4 + rr;
                int gn = n0 + wc * 64 + ni * 16 + r;
                float v = acc[mi][ni][rr];
                int b = gm >> 11, t = gm & 2047;
                int sel = gn >> 10, nn = gn & 1023;
                int h = nn >> 6, d = nn & 63;
                if (sel == 0)
                    Qb[((size_t)(b * 16 + h) * 2048 + t) * 64 + d] = f2bf(v);
                else if (sel == 1)
                    Kb[((size_t)(b * 16 + h) * 2048 + t) * 64 + d] = f2bf(v);
                else
                    Vtb[((size_t)(b * 16 + h) * 64 + d) * 2048 + t] = f2bf(v);
            }
        }
    }
}

// Final projection, same core, fp32 out. M=8192, N=1024, K=1024.
// Grid 256 blocks (8 n-tiles x 32 m-tiles) = exactly 1 block/CU round.
__global__ __launch_bounds__(512, 4) void gemm_out(const unsigned short* __restrict__ A,
                                                   const unsigned short* __restrict__ B,
                                                   float* __restrict__ out) {
    __shared__ unsigned short As[3][8192];
    __shared__ unsigned short Bs[3][4096];
    int id = blockIdx.x;
    int bx = id & 7, by = id >> 3;
    int m0 = by * 256, n0 = bx * 128;

    f32x4 acc[4][4];
    gemm_hp(A, B, m0, n0, As, Bs, acc);

    int tid = threadIdx.x;
    int wave = tid >> 6, lane = tid & 63;
    int r = lane & 15, q = lane >> 4;
    int wr = wave >> 1, wc = wave & 1;
#pragma unroll
    for (int mi = 0; mi < 4; mi++)
#pragma unroll
        for (int ni = 0; ni < 4; ni++)
#pragma unroll
            for (int rr = 0; rr < 4; rr++) {
                int gm = m0 + wr * 64 + mi * 16 + q * 4 + rr;
                int gn = n0 + wc * 64 + ni * 16 + r;
                out[(size_t)gm * 1024 + gn] = acc[mi][ni][rr];
            }
}

// Suffix sums of V at 64-key granularity: SV[bh][j][d] = sum_{k >= 64j} V[bh][k][d]
__global__ __launch_bounds__(256) void suffix_sv(const unsigned short* __restrict__ Vt,
                                                 float* __restrict__ SV) {
    __shared__ float bsum[32][64];
    int bh = blockIdx.x;
    int d = threadIdx.x & 63, c = threadIdx.x >> 6;
    const unsigned short* base = Vt + ((size_t)bh * 64 + d) * T_SEQ;
#pragma unroll
    for (int jj = 0; jj < 8; jj++) {
        int j = c * 8 + jj;
        float s = 0.f;
#pragma unroll
        for (int t8 = 0; t8 < 8; t8++) {
            bf16x8 v = *(const bf16x8*)(base + j * 64 + t8 * 8);
#pragma unroll
            for (int e = 0; e < 8; e++) s += bf2f((unsigned short)v[e]);
        }
        bsum[j][d] = s;
    }
    __syncthreads();
    if (threadIdx.x < 64) {
        float run = 0.f;
        for (int j = 31; j >= 0; j--) {
            run += bsum[j][d];
            SV[((size_t)bh * 32 + j) * 64 + d] = run;
        }
    }
}

// Flash attention (R6 structure, unchanged): transposed-S, no-max softmax,
// analytic -10 tail, register-prefetch staging, 2-phase uniform load balance.
#define KST 72
#define VST 72
#define PST 72
__global__ __launch_bounds__(256) void attn(const unsigned short* __restrict__ Q,
                                            const unsigned short* __restrict__ Kg,
                                            const unsigned short* __restrict__ Vt,
                                            const float* __restrict__ SV,
                                            unsigned short* __restrict__ Y) {
    __shared__ unsigned short Ks[64 * KST];    // [key][d]
    __shared__ unsigned short Vs[64 * VST];    // [d][key]
    __shared__ unsigned short Ps[4][16 * PST]; // per wave: [query][key]
    int bh = blockIdx.y;
    int tid = threadIdx.x, wave = tid >> 6, lane = tid & 63;
    int r = lane & 15, qd = lane >> 4;
    int b = bh >> 4, h = bh & 15;

    int srow = tid >> 2, scol = (tid & 3) * 16;  // staging: 64 rows x 128B
    const unsigned short* kg = Kg + ((size_t)bh * T_SEQ + srow) * 64 + scol;
    const unsigned short* vg = Vt + ((size_t)bh * 64 + srow) * T_SEQ + scol;
    const float scale = 0.125f;

#pragma unroll
    for (int phase = 0; phase < 2; phase++) {
        int qi = phase == 0 ? 16 + (int)blockIdx.x : 15 - (int)blockIdx.x;
        int q0 = qi * 64;
        int query = q0 + wave * 16 + r;

        const unsigned short* qptr = Q + ((size_t)bh * T_SEQ + query) * 64 + qd * 8;
        bf16x8 qf0 = *(const bf16x8*)qptr;
        bf16x8 qf1 = *(const bf16x8*)(qptr + 32);

        float l_lane = 0.0f;
        f32x4 o[4];
#pragma unroll
        for (int n = 0; n < 4; n++) o[n] = (f32x4){0.f, 0.f, 0.f, 0.f};

        bf16x8 pk0 = *(const bf16x8*)(kg);
        bf16x8 pk1 = *(const bf16x8*)(kg + 8);
        bf16x8 pv0 = *(const bf16x8*)(vg);
        bf16x8 pv1 = *(const bf16x8*)(vg + 8);

        int iters = qi + 1;
        for (int it = 0; it < iters; ++it) {
            __syncthreads();
            *(bf16x8*)&Ks[srow * KST + scol]     = pk0;
            *(bf16x8*)&Ks[srow * KST + scol + 8] = pk1;
            *(bf16x8*)&Vs[srow * VST + scol]     = pv0;
            *(bf16x8*)&Vs[srow * VST + scol + 8] = pv1;
            __syncthreads();
            if (it + 1 < iters) {
                size_t kn = (size_t)(it + 1) * 64;
                pk0 = *(const bf16x8*)(kg + kn * 64);
                pk1 = *(const bf16x8*)(kg + kn * 64 + 8);
                pv0 = *(const bf16x8*)(vg + kn);
                pv1 = *(const bf16x8*)(vg + kn + 8);
            }

            int k0 = it * 64;
            f32x4 st[4];
#pragma unroll
            for (int t = 0; t < 4; t++) {
                bf16x8 kf0 = *(const bf16x8*)&Ks[(t * 16 + r) * KST + qd * 8];
                bf16x8 kf1 = *(const bf16x8*)&Ks[(t * 16 + r) * KST + 32 + qd * 8];
                st[t] = (f32x4){0.f, 0.f, 0.f, 0.f};
                st[t] = __builtin_amdgcn_mfma_f32_16x16x32_bf16(kf0, qf0, st[t], 0, 0, 0);
                st[t] = __builtin_amdgcn_mfma_f32_16x16x32_bf16(kf1, qf1, st[t], 0, 0, 0);
            }

            float p[4][4], sum = 0.f;
            bool anymask = (k0 + 63 > q0 + wave * 16);  // wave-uniform
            if (anymask) {
#pragma unroll
                for (int t = 0; t < 4; t++)
#pragma unroll
                    for (int e = 0; e < 4; e++) {
                        int kgidx = k0 + t * 16 + qd * 4 + e;
                        float pe = __expf(st[t][e] * scale);
                        p[t][e] = (kgidx <= query) ? pe : EXPM10;
                        sum += p[t][e];
                    }
            } else {
#pragma unroll
                for (int t = 0; t < 4; t++)
#pragma unroll
                    for (int e = 0; e < 4; e++) {
                        p[t][e] = __expf(st[t][e] * scale);
                        sum += p[t][e];
                    }
            }
            l_lane += sum;

#pragma unroll
            for (int t = 0; t < 4; t++) {
                ushort4 pk;
                pk.x = f2bf(p[t][0]); pk.y = f2bf(p[t][1]);
                pk.z = f2bf(p[t][2]); pk.w = f2bf(p[t][3]);
                *(ushort4*)&Ps[wave][r * PST + t * 16 + qd * 4] = pk;
            }
            __builtin_amdgcn_sched_barrier(0);  // wave-private Ps: keep order

            bf16x8 pf0 = *(const bf16x8*)&Ps[wave][r * PST + qd * 8];
            bf16x8 pf1 = *(const bf16x8*)&Ps[wave][r * PST + 32 + qd * 8];
#pragma unroll
            for (int n = 0; n < 4; n++) {
                bf16x8 vf0 = *(const bf16x8*)&Vs[(n * 16 + r) * VST + qd * 8];
                bf16x8 vf1 = *(const bf16x8*)&Vs[(n * 16 + r) * VST + 32 + qd * 8];
                o[n] = __builtin_amdgcn_mfma_f32_16x16x32_bf16(vf0, pf0, o[n], 0, 0, 0);
                o[n] = __builtin_amdgcn_mfma_f32_16x16x32_bf16(vf1, pf1, o[n], 0, 0, 0);
            }
        }

        float l_i = l_lane;
        l_i += __shfl_xor(l_i, 16);
        l_i += __shfl_xor(l_i, 32);

        int j = qi + 1;
        float pm = 0.f, tail_l = 0.f;
        float sv[4][4];
#pragma unroll
        for (int n = 0; n < 4; n++)
#pragma unroll
            for (int e = 0; e < 4; e++) sv[n][e] = 0.f;
        if (j < 32) {
            pm = EXPM10;
            tail_l = (float)(T_SEQ - 64 * j) * pm;
            const float* svp = SV + ((size_t)bh * 32 + j) * 64;
#pragma unroll
            for (int n = 0; n < 4; n++) {
                float4 f = *(const float4*)(svp + n * 16 + qd * 4);
                sv[n][0] = f.x; sv[n][1] = f.y; sv[n][2] = f.z; sv[n][3] = f.w;
            }
        }
        float inv = 1.0f / (l_i + tail_l);
#pragma unroll
        for (int n = 0; n < 4; n++) {
            ushort4 yk;
            yk.x = f2bf((o[n][0] + pm * sv[n][0]) * inv);
            yk.y = f2bf((o[n][1] + pm * sv[n][1]) * inv);
            yk.z = f2bf((o[n][2] + pm * sv[n][2]) * inv);
            yk.w = f2bf((o[n][3] + pm * sv[n][3]) * inv);
            *(ushort4*)&Y[(((size_t)b * T_SEQ + query) * 16 + h) * 64 + n * 16 + qd * 4] = yk;
        }
    }
}

extern "C" void kernel_launch(void* const* d_in, const int* in_sizes, int n_in,
                              void* d_out, int out_size, void* d_ws, size_t ws_size,
                              hipStream_t stream) {
    const float* x  = (const float*)d_in[0];
    const float* wq = (const float*)d_in[1];
    const float* wk = (const float*)d_in[2];
    const float* wv = (const float*)d_in[3];
    const float* wo = (const float*)d_in[4];

    char* ws = (char*)d_ws;
    const size_t MB = 1u << 20;
    unsigned short* xb   = (unsigned short*)(ws);            // 16 MB (reused as Yb)
    unsigned short* Qb   = (unsigned short*)(ws + 16 * MB);  // 16 MB
    unsigned short* Kb   = (unsigned short*)(ws + 32 * MB);  // 16 MB
    unsigned short* Vtb  = (unsigned short*)(ws + 48 * MB);  // 16 MB
    unsigned short* wqkv = (unsigned short*)(ws + 64 * MB);  // 6 MB
    unsigned short* wob  = (unsigned short*)(ws + 70 * MB);  // 2 MB -> 72 MB total
    unsigned short* Yb   = xb;
    float* SVf = (float*)d_out;  // scratch until final gemm overwrites d_out

    cvt_bf16<<<8192, 256, 0, stream>>>(x, xb, 2097152);
    cvt_w<<<4096, 256, 0, stream>>>(wq, wk, wv, wo, wqkv, wob);

    gemm_qkv<<<768, 512, 0, stream>>>(xb, wqkv, Qb, Kb, Vtb);

    suffix_sv<<<64, 256, 0, stream>>>(Vtb, SVf);

    attn<<<dim3(16, 64), 256, 0, stream>>>(Qb, Kb, Vtb, SVf, Yb);

    gemm_out<<<256, 512, 0, stream>>>(Yb, wob, (float*)d_out);
}